// Round 1
// baseline (3571.309 us; speedup 1.0000x reference)
//
#include <hip/hip_runtime.h>
#include <cstdint>

// ---------------------------------------------------------------------------
// QLoRA block: 4 big bf16-MFMA GEMMs + NF4 dequant + lora folded as extra K.
// M=4096 tokens, H=4096, I=14336, R=16. All bf16 handled as unsigned short.
// ---------------------------------------------------------------------------

typedef __attribute__((ext_vector_type(4))) float f32x4;
typedef __attribute__((ext_vector_type(8))) short s16x8;
typedef __attribute__((ext_vector_type(4))) int   i32x4;

__constant__ float NF4_TBL[16] = {
  -1.0f, -0.6961928009986877f, -0.5250730514526367f, -0.39491748809814453f,
  -0.28444138169288635f, -0.18477343022823334f, -0.09105003625154495f, 0.0f,
   0.07958029955625534f, 0.16093020141124725f, 0.24611230194568634f,
   0.33791524171829224f, 0.44070982933044434f, 0.5626170039176941f,
   0.7229568362236023f, 1.0f };

__device__ __forceinline__ unsigned short f2bf(float f){
  unsigned u = __builtin_bit_cast(unsigned, f);
  u += 0x7fffu + ((u >> 16) & 1u);              // RNE
  return (unsigned short)(u >> 16);
}
__device__ __forceinline__ float bf2f(unsigned short h){
  return __builtin_bit_cast(float, ((unsigned)h) << 16);
}

// async global->LDS, 16B per lane. LDS dst must be wave-uniform base (lane*16 implicit).
__device__ __forceinline__ void gll16(const unsigned short* g, unsigned short* l){
  __builtin_amdgcn_global_load_lds((__attribute__((address_space(1))) unsigned int*)g,
                                   (__attribute__((address_space(3))) unsigned int*)l,
                                   16, 0, 0);
}

// ---------------------------------------------------------------------------
// elementwise fp32 -> bf16 (8 elems/thread)
__global__ void cast_f32_bf16(unsigned short* __restrict__ dst,
                              const float* __restrict__ src, long long n8){
  const long long i = (long long)blockIdx.x * blockDim.x + threadIdx.x;
  if (i >= n8) return;
  const f32x4 a = *(const f32x4*)(src + i*8);
  const f32x4 b = *(const f32x4*)(src + i*8 + 4);
  s16x8 o;
  o[0]=(short)f2bf(a.x); o[1]=(short)f2bf(a.y); o[2]=(short)f2bf(a.z); o[3]=(short)f2bf(a.w);
  o[4]=(short)f2bf(b.x); o[5]=(short)f2bf(b.y); o[6]=(short)f2bf(b.z); o[7]=(short)f2bf(b.w);
  *(s16x8*)(dst + i*8) = o;
}

// pack lora B [N,16] fp32 -> bf16 [N,64] at column offset (rest stays zero)
__global__ void pack_bl_kernel(unsigned short* __restrict__ dst,
                               const float* __restrict__ src,
                               int N, int coloff, float mul){
  const int i = blockIdx.x * blockDim.x + threadIdx.x;
  if (i >= N * 16) return;
  const int n = i >> 4, r = i & 15;
  dst[(size_t)n * 64 + coloff + r] = f2bf(src[i] * mul);
}

// NF4 dequant: dst[n][k] = NF4[codes[n][k]] * scales[n][k/64] * mul   (8 elems/thread)
__global__ void dequant1_kernel(unsigned short* __restrict__ dst,
                                const int* __restrict__ codes,
                                const float* __restrict__ scales, int K, float mul){
  const int k = (blockIdx.x * blockDim.x + threadIdx.x) * 8;
  if (k >= K) return;
  const size_t n = blockIdx.y;
  const size_t base = n * (size_t)K + k;
  const float s = scales[n * (size_t)(K >> 6) + (k >> 6)] * mul;
  const i32x4 c0 = *(const i32x4*)(codes + base);
  const i32x4 c1 = *(const i32x4*)(codes + base + 4);
  s16x8 o;
  o[0]=(short)f2bf(NF4_TBL[c0.x]*s); o[1]=(short)f2bf(NF4_TBL[c0.y]*s);
  o[2]=(short)f2bf(NF4_TBL[c0.z]*s); o[3]=(short)f2bf(NF4_TBL[c0.w]*s);
  o[4]=(short)f2bf(NF4_TBL[c1.x]*s); o[5]=(short)f2bf(NF4_TBL[c1.y]*s);
  o[6]=(short)f2bf(NF4_TBL[c1.z]*s); o[7]=(short)f2bf(NF4_TBL[c1.w]*s);
  *(s16x8*)(dst + base) = o;
}

// Wsum = (Wq + Wk + Wv) * mul, dequantized on the fly (H=4096 hardcoded strides)
__global__ void dequant3_kernel(unsigned short* __restrict__ dst,
                                const int* __restrict__ codes,
                                const float* __restrict__ scales, int K, float mul){
  const int k = (blockIdx.x * blockDim.x + threadIdx.x) * 8;
  if (k >= K) return;
  const size_t n = blockIdx.y;
  const size_t base = n * (size_t)K + k;
  const size_t CS = (size_t)4096 * 4096;
  const size_t SS = (size_t)4096 * 64;
  float acc[8] = {0.f,0.f,0.f,0.f,0.f,0.f,0.f,0.f};
  #pragma unroll
  for (int t = 0; t < 3; ++t){
    const float s = scales[t * SS + n * (size_t)(K >> 6) + (k >> 6)];
    const i32x4 c0 = *(const i32x4*)(codes + t * CS + base);
    const i32x4 c1 = *(const i32x4*)(codes + t * CS + base + 4);
    acc[0]+=NF4_TBL[c0.x]*s; acc[1]+=NF4_TBL[c0.y]*s; acc[2]+=NF4_TBL[c0.z]*s; acc[3]+=NF4_TBL[c0.w]*s;
    acc[4]+=NF4_TBL[c1.x]*s; acc[5]+=NF4_TBL[c1.y]*s; acc[6]+=NF4_TBL[c1.z]*s; acc[7]+=NF4_TBL[c1.w]*s;
  }
  s16x8 o;
  #pragma unroll
  for (int e = 0; e < 8; ++e) o[e] = (short)f2bf(acc[e] * mul);
  *(s16x8*)(dst + base) = o;
}

// t = act[M,K](bf16) @ Ab[16,K](bf16)^T -> tout[M,64] bf16 at column coloff.
// One wave per 16-row tile; A-frag m=lane&15, B-frag n=lane&15, k=quad*8+j.
__global__ __launch_bounds__(256)
void lora_t_kernel(const unsigned short* __restrict__ act,
                   const unsigned short* __restrict__ Ab,
                   unsigned short* __restrict__ tout, int K, int coloff){
  const int lane = threadIdx.x & 63, wave = threadIdx.x >> 6;
  const int m0 = (blockIdx.x * 4 + wave) * 16;
  const int q = lane >> 4, r = lane & 15;
  const unsigned short* ap = act + (size_t)(m0 + r) * K + q * 8;
  const unsigned short* bp = Ab  + (size_t)r * K + q * 8;
  f32x4 acc = {0.f, 0.f, 0.f, 0.f};
  for (int k = 0; k < K; k += 32){
    const s16x8 a = *(const s16x8*)ap;
    const s16x8 b = *(const s16x8*)bp;
    acc = __builtin_amdgcn_mfma_f32_16x16x32_bf16(a, b, acc, 0, 0, 0);
    ap += 32; bp += 32;
  }
  // D: row m = quad*4+reg, col n = lane&15   [measured m89]
  #pragma unroll
  for (int rr = 0; rr < 4; ++rr)
    tout[(size_t)(m0 + q*4 + rr) * 64 + coloff + r] = f2bf(acc[rr]);
}

// h = silu(gate) * up ; gu is [M, 2I] with gate in cols [0,I), up in [I,2I)
__global__ void silu_mul_kernel(unsigned short* __restrict__ h,
                                const unsigned short* __restrict__ gu){
  const int k8 = blockIdx.x * blockDim.x + threadIdx.x;  // < I/8 = 1792
  const size_t row = blockIdx.y;
  const s16x8 g8 = *(const s16x8*)(gu + row * 28672 + (size_t)k8 * 8);
  const s16x8 u8 = *(const s16x8*)(gu + row * 28672 + 14336 + (size_t)k8 * 8);
  s16x8 o;
  #pragma unroll
  for (int e = 0; e < 8; ++e){
    const float g = bf2f((unsigned short)g8[e]);
    const float u = bf2f((unsigned short)u8[e]);
    const float s = g / (1.f + __expf(-g));
    o[e] = (short)f2bf(s * u);
  }
  *(s16x8*)(h + row * 14336 + (size_t)k8 * 8) = o;
}

// ---------------------------------------------------------------------------
// Main GEMM: C[M,N] = A[M,K] @ B[N,K]^T, bf16 in / fp32 acc.
// 128x128 tile, 256 thr = 4 waves (2x2), wave does 64x64 via 4x4 mfma 16x16x32.
// Staging: global_load_lds 16B/lane, XOR chunk swizzle (col^=row&7) so the
// ds_read_b128 fragment reads are 2-way-conflict-only (free, m136).
// Lora is one extra K=64 iteration sourced from tL[M,64]/bL[N,64] (zero-padded).
// EPI: 0 = store bf16; 1 = o-proj (x1 = res + v, store fp32+bf16); 2 = down (out = res + v, fp32).
template<int EPI>
__global__ __launch_bounds__(256)
void gemm_kernel(const unsigned short* __restrict__ Aact,
                 const unsigned short* __restrict__ Bw,
                 const unsigned short* __restrict__ tL,
                 const unsigned short* __restrict__ bL,
                 int K, int ldC,
                 const float* __restrict__ resIn,
                 float* __restrict__ outF,
                 unsigned short* __restrict__ outB){
  __shared__ unsigned short As[128 * 64];
  __shared__ unsigned short Bs[128 * 64];
  const int tid  = threadIdx.x;
  const int lane = tid & 63;
  const int wave = tid >> 6;
  const int m0 = blockIdx.x << 7;   // x = M tiles so consecutive blocks share B-panel
  const int n0 = blockIdx.y << 7;

  // staging map: chunk c = tid + 256p ; row = c/8, slot-col = c%8, data-col = slot^ (row&7)
  const int srow  = tid >> 3;
  const int scol  = tid & 7;
  const int swcol = scol ^ (srow & 7);
  const unsigned short* gA = Aact + (size_t)(m0 + srow) * K + swcol * 8;
  const unsigned short* gB = Bw   + (size_t)(n0 + srow) * K + swcol * 8;
  const int ldsbase = wave * 512;   // wave*64 chunks * 8 shorts

  const int wm = wave >> 1, wn = wave & 1;
  const int q = lane >> 4, r15 = lane & 15;
  int aoff[4][2], boff[4][2];
  #pragma unroll
  for (int i = 0; i < 4; ++i){
    const int ml = wm*64 + i*16 + r15;
    const int nl = wn*64 + i*16 + r15;
    #pragma unroll
    for (int kk = 0; kk < 2; ++kk){
      aoff[i][kk] = ml*64 + ((((kk<<2)|q) ^ (ml & 7)) * 8);
      boff[i][kk] = nl*64 + ((((kk<<2)|q) ^ (nl & 7)) * 8);
    }
  }

  f32x4 acc[4][4];
  #pragma unroll
  for (int i = 0; i < 4; ++i)
    #pragma unroll
    for (int j = 0; j < 4; ++j) acc[i][j] = (f32x4){0.f,0.f,0.f,0.f};

  const int nK = K >> 6;
  size_t koff = 0;
  for (int kt = 0; kt <= nK; ++kt){
    const unsigned short* pa; const unsigned short* pb; size_t rs;
    if (kt < nK){ pa = gA + koff; pb = gB + koff; rs = (size_t)K * 32; }
    else {  // lora extra iteration: [*,64] row-major, row stride 64
      pa = tL + (size_t)(m0 + srow) * 64 + swcol * 8;
      pb = bL + (size_t)(n0 + srow) * 64 + swcol * 8;
      rs = 64 * 32;
    }
    #pragma unroll
    for (int p = 0; p < 4; ++p){
      gll16(pa + rs * p, As + ldsbase + p * 2048);
      gll16(pb + rs * p, Bs + ldsbase + p * 2048);
    }
    __syncthreads();                       // drains vmcnt(0) + barrier
    #pragma unroll
    for (int kk = 0; kk < 2; ++kk){
      s16x8 af[4], bfr[4];
      #pragma unroll
      for (int i = 0; i < 4; ++i) af[i]  = *(const s16x8*)(As + aoff[i][kk]);
      #pragma unroll
      for (int j = 0; j < 4; ++j) bfr[j] = *(const s16x8*)(Bs + boff[j][kk]);
      #pragma unroll
      for (int i = 0; i < 4; ++i)
        #pragma unroll
        for (int j = 0; j < 4; ++j)
          acc[i][j] = __builtin_amdgcn_mfma_f32_16x16x32_bf16(af[i], bfr[j], acc[i][j], 0, 0, 0);
    }
    __syncthreads();                       // LDS safe to overwrite
    koff += 64;
  }

  // epilogue: D row m = quad*4+reg, col n = lane&15 [measured m89]
  #pragma unroll
  for (int i = 0; i < 4; ++i){
    const int gm = m0 + wm*64 + i*16 + q*4;
    #pragma unroll
    for (int j = 0; j < 4; ++j){
      const int gn = n0 + wn*64 + j*16 + r15;
      #pragma unroll
      for (int rr = 0; rr < 4; ++rr){
        const size_t idx = (size_t)(gm + rr) * ldC + gn;
        const float v = acc[i][j][rr];
        if constexpr (EPI == 0){
          outB[idx] = f2bf(v);
        } else if constexpr (EPI == 1){
          const float x1 = resIn[idx] + v;
          outF[idx] = x1;
          outB[idx] = f2bf(x1);
        } else {
          outF[idx] = resIn[idx] + v;
        }
      }
    }
  }
}

// ---------------------------------------------------------------------------
extern "C" void kernel_launch(void* const* d_in, const int* in_sizes, int n_in,
                              void* d_out, int out_size, void* d_ws, size_t ws_size,
                              hipStream_t stream){
  (void)in_sizes; (void)n_in; (void)out_size; (void)ws_size;
  constexpr int M = 4096, H = 4096, I = 14336, I2 = 28672;

  const float* x            = (const float*)d_in[0];
  const int*   codes_attn   = (const int*)  d_in[1];
  const float* scales_attn  = (const float*)d_in[2];
  const int*   codes_gu     = (const int*)  d_in[3];
  const float* scales_gu    = (const float*)d_in[4];
  const int*   codes_down   = (const int*)  d_in[5];
  const float* scales_down  = (const float*)d_in[6];
  const float* lora_A_h     = (const float*)d_in[7];
  const float* lora_A_down  = (const float*)d_in[8];
  const float* lora_B_attn  = (const float*)d_in[9];
  const float* lora_B_gu    = (const float*)d_in[10];
  const float* lora_B_down  = (const float*)d_in[11];
  float* out = (float*)d_out;

  char* ws = (char*)d_ws;
  size_t off = 0;
  auto take = [&](size_t b){ void* p = ws + off; off += b; return p; };
  unsigned short* xb    = (unsigned short*)take((size_t)M*H*2);    // x as bf16
  unsigned short* W1    = (unsigned short*)take((size_t)H*H*2);    // Wsum, then Wo
  unsigned short* attn  = (unsigned short*)take((size_t)M*H*2);
  float*          x1f   = (float*)         take((size_t)M*H*4);
  unsigned short* x1b   = (unsigned short*)take((size_t)M*H*2);
  unsigned short* Wgu   = (unsigned short*)take((size_t)I2*H*2);   // then Wd
  unsigned short* gu    = (unsigned short*)take((size_t)M*I2*2);
  unsigned short* hbuf  = (unsigned short*)take((size_t)M*I*2);
  unsigned short* t1    = (unsigned short*)take((size_t)M*64*2);   // zeroed arena starts here
  unsigned short* t2    = (unsigned short*)take((size_t)M*64*2);
  unsigned short* t3    = (unsigned short*)take((size_t)M*64*2);
  unsigned short* t4    = (unsigned short*)take((size_t)M*64*2);
  unsigned short* bl_at = (unsigned short*)take((size_t)H*64*2);
  unsigned short* bl_o  = (unsigned short*)take((size_t)H*64*2);
  unsigned short* bl_gu = (unsigned short*)take((size_t)I2*64*2);
  unsigned short* bl_dn = (unsigned short*)take((size_t)H*64*2);
  const size_t zbytes = (size_t)((char*)ws + off - (char*)t1);
  unsigned short* al_h  = (unsigned short*)take((size_t)6*16*H*2); // lora A (h-side) bf16
  unsigned short* al_dn = (unsigned short*)take((size_t)16*I*2);   // lora A down bf16

  // zero the t / bl arena (ws is poisoned 0xAA before every call)
  hipMemsetAsync(t1, 0, zbytes, stream);

  // casts
  cast_f32_bf16<<<dim3((M*(size_t)H/8)/256), 256, 0, stream>>>(xb, x, (long long)M*H/8);
  cast_f32_bf16<<<dim3(192), 256, 0, stream>>>(al_h,  lora_A_h,    (long long)6*16*H/8);
  cast_f32_bf16<<<dim3(112), 256, 0, stream>>>(al_dn, lora_A_down, (long long)16*I/8);

  // pack lora B panels into [N,64] bf16
  for (int p = 0; p < 3; ++p)
    pack_bl_kernel<<<dim3(256), 256, 0, stream>>>(bl_at, lora_B_attn + (size_t)p*H*16, H, p*16, 1.f/3.f);
  pack_bl_kernel<<<dim3(256), 256, 0, stream>>>(bl_o, lora_B_attn + (size_t)3*H*16, H, 0, 1.f);
  pack_bl_kernel<<<dim3(896), 256, 0, stream>>>(bl_gu, lora_B_gu, I, 0, 1.f);
  pack_bl_kernel<<<dim3(896), 256, 0, stream>>>(bl_gu + (size_t)I*64, lora_B_gu + (size_t)I*16, I, 16, 1.f);
  pack_bl_kernel<<<dim3(256), 256, 0, stream>>>(bl_dn, lora_B_down, H, 0, 1.f);

  // t1 = xb @ [Aq;Ak;Av]^T  (1/3 folded into bl_at)
  for (int p = 0; p < 3; ++p)
    lora_t_kernel<<<dim3(M/64), 256, 0, stream>>>(xb, al_h + (size_t)p*16*H, t1, H, p*16);

  // G1: attn = xb @ Wsum^T + lora      (Wsum = (Wq+Wk+Wv)/3)
  dequant3_kernel<<<dim3(H/2048, H), 256, 0, stream>>>(W1, codes_attn, scales_attn, H, 1.f/3.f);
  gemm_kernel<0><<<dim3(32, 32), 256, 0, stream>>>(xb, W1, t1, bl_at, H, H, nullptr, nullptr, attn);

  // G2: x1 = x + attn @ Wo^T + lora
  dequant1_kernel<<<dim3(H/2048, H), 256, 0, stream>>>(W1, codes_attn + (size_t)3*H*H,
                                                       scales_attn + (size_t)3*H*64, H, 1.f);
  lora_t_kernel<<<dim3(M/64), 256, 0, stream>>>(attn, al_h + (size_t)3*16*H, t2, H, 0);
  gemm_kernel<1><<<dim3(32, 32), 256, 0, stream>>>(attn, W1, t2, bl_o, H, H, x, x1f, x1b);

  // G3: gu = x1 @ [Wg;Wu]^T + lora (gate cols [0,I), up cols [I,2I))
  lora_t_kernel<<<dim3(M/64), 256, 0, stream>>>(x1b, al_h + (size_t)4*16*H, t3, H, 0);
  lora_t_kernel<<<dim3(M/64), 256, 0, stream>>>(x1b, al_h + (size_t)5*16*H, t3, H, 16);
  dequant1_kernel<<<dim3(H/2048, I2), 256, 0, stream>>>(Wgu, codes_gu, scales_gu, H, 1.f);
  gemm_kernel<0><<<dim3(32, 224), 256, 0, stream>>>(x1b, Wgu, t3, bl_gu, H, I2, nullptr, nullptr, gu);

  // h = silu(g) * u
  silu_mul_kernel<<<dim3(I/2048, M), 256, 0, stream>>>(hbuf, gu);

  // G5: out = x1 + h @ Wd^T + lora
  lora_t_kernel<<<dim3(M/64), 256, 0, stream>>>(hbuf, al_dn, t4, I, 0);
  dequant1_kernel<<<dim3(I/2048, H), 256, 0, stream>>>(Wgu, codes_down, scales_down, I, 1.f);
  gemm_kernel<2><<<dim3(32, 32), 256, 0, stream>>>(hbuf, Wgu, t4, bl_dn, I, H, x1f, out, nullptr);
}

// Round 2
// 3221.400 us; speedup vs baseline: 1.1086x; 1.1086x over previous
//
#include <hip/hip_runtime.h>
#include <cstdint>

// ---------------------------------------------------------------------------
// QLoRA block: 4 big bf16-MFMA GEMMs + NF4 dequant + lora folded as extra K.
// M=4096 tokens, H=4096, I=14336, R=16. All bf16 handled as unsigned short.
// R2: lora_t split-K rewrite (was 64-block latency-bound, ~1.3ms total).
// ---------------------------------------------------------------------------

typedef __attribute__((ext_vector_type(4))) float f32x4;
typedef __attribute__((ext_vector_type(8))) short s16x8;
typedef __attribute__((ext_vector_type(4))) int   i32x4;

__constant__ float NF4_TBL[16] = {
  -1.0f, -0.6961928009986877f, -0.5250730514526367f, -0.39491748809814453f,
  -0.28444138169288635f, -0.18477343022823334f, -0.09105003625154495f, 0.0f,
   0.07958029955625534f, 0.16093020141124725f, 0.24611230194568634f,
   0.33791524171829224f, 0.44070982933044434f, 0.5626170039176941f,
   0.7229568362236023f, 1.0f };

__device__ __forceinline__ unsigned short f2bf(float f){
  unsigned u = __builtin_bit_cast(unsigned, f);
  u += 0x7fffu + ((u >> 16) & 1u);              // RNE
  return (unsigned short)(u >> 16);
}
__device__ __forceinline__ float bf2f(unsigned short h){
  return __builtin_bit_cast(float, ((unsigned)h) << 16);
}

// async global->LDS, 16B per lane. LDS dst must be wave-uniform base (lane*16 implicit).
__device__ __forceinline__ void gll16(const unsigned short* g, unsigned short* l){
  __builtin_amdgcn_global_load_lds((__attribute__((address_space(1))) unsigned int*)g,
                                   (__attribute__((address_space(3))) unsigned int*)l,
                                   16, 0, 0);
}

// ---------------------------------------------------------------------------
// elementwise fp32 -> bf16 (8 elems/thread)
__global__ void cast_f32_bf16(unsigned short* __restrict__ dst,
                              const float* __restrict__ src, long long n8){
  const long long i = (long long)blockIdx.x * blockDim.x + threadIdx.x;
  if (i >= n8) return;
  const f32x4 a = *(const f32x4*)(src + i*8);
  const f32x4 b = *(const f32x4*)(src + i*8 + 4);
  s16x8 o;
  o[0]=(short)f2bf(a.x); o[1]=(short)f2bf(a.y); o[2]=(short)f2bf(a.z); o[3]=(short)f2bf(a.w);
  o[4]=(short)f2bf(b.x); o[5]=(short)f2bf(b.y); o[6]=(short)f2bf(b.z); o[7]=(short)f2bf(b.w);
  *(s16x8*)(dst + i*8) = o;
}

// pack lora B [N,16] fp32 -> bf16 [N,64] at column offset (rest stays zero)
__global__ void pack_bl_kernel(unsigned short* __restrict__ dst,
                               const float* __restrict__ src,
                               int N, int coloff, float mul){
  const int i = blockIdx.x * blockDim.x + threadIdx.x;
  if (i >= N * 16) return;
  const int n = i >> 4, r = i & 15;
  dst[(size_t)n * 64 + coloff + r] = f2bf(src[i] * mul);
}

// NF4 dequant: dst[n][k] = NF4[codes[n][k]] * scales[n][k/64] * mul   (8 elems/thread)
__global__ void dequant1_kernel(unsigned short* __restrict__ dst,
                                const int* __restrict__ codes,
                                const float* __restrict__ scales, int K, float mul){
  const int k = (blockIdx.x * blockDim.x + threadIdx.x) * 8;
  if (k >= K) return;
  const size_t n = blockIdx.y;
  const size_t base = n * (size_t)K + k;
  const float s = scales[n * (size_t)(K >> 6) + (k >> 6)] * mul;
  const i32x4 c0 = *(const i32x4*)(codes + base);
  const i32x4 c1 = *(const i32x4*)(codes + base + 4);
  s16x8 o;
  o[0]=(short)f2bf(NF4_TBL[c0.x]*s); o[1]=(short)f2bf(NF4_TBL[c0.y]*s);
  o[2]=(short)f2bf(NF4_TBL[c0.z]*s); o[3]=(short)f2bf(NF4_TBL[c0.w]*s);
  o[4]=(short)f2bf(NF4_TBL[c1.x]*s); o[5]=(short)f2bf(NF4_TBL[c1.y]*s);
  o[6]=(short)f2bf(NF4_TBL[c1.z]*s); o[7]=(short)f2bf(NF4_TBL[c1.w]*s);
  *(s16x8*)(dst + base) = o;
}

// Wsum = (Wq + Wk + Wv) * mul, dequantized on the fly (H=4096 hardcoded strides)
__global__ void dequant3_kernel(unsigned short* __restrict__ dst,
                                const int* __restrict__ codes,
                                const float* __restrict__ scales, int K, float mul){
  const int k = (blockIdx.x * blockDim.x + threadIdx.x) * 8;
  if (k >= K) return;
  const size_t n = blockIdx.y;
  const size_t base = n * (size_t)K + k;
  const size_t CS = (size_t)4096 * 4096;
  const size_t SS = (size_t)4096 * 64;
  float acc[8] = {0.f,0.f,0.f,0.f,0.f,0.f,0.f,0.f};
  #pragma unroll
  for (int t = 0; t < 3; ++t){
    const float s = scales[t * SS + n * (size_t)(K >> 6) + (k >> 6)];
    const i32x4 c0 = *(const i32x4*)(codes + t * CS + base);
    const i32x4 c1 = *(const i32x4*)(codes + t * CS + base + 4);
    acc[0]+=NF4_TBL[c0.x]*s; acc[1]+=NF4_TBL[c0.y]*s; acc[2]+=NF4_TBL[c0.z]*s; acc[3]+=NF4_TBL[c0.w]*s;
    acc[4]+=NF4_TBL[c1.x]*s; acc[5]+=NF4_TBL[c1.y]*s; acc[6]+=NF4_TBL[c1.z]*s; acc[7]+=NF4_TBL[c1.w]*s;
  }
  s16x8 o;
  #pragma unroll
  for (int e = 0; e < 8; ++e) o[e] = (short)f2bf(acc[e] * mul);
  *(s16x8*)(dst + base) = o;
}

// ---------------------------------------------------------------------------
// t = act[M,K] @ Ab[NP*16,K]^T -> tout[M,64] bf16, panel p lands at cols
// [coloff+16p, coloff+16p+16). Split-K: one block per 16-row M-tile (grid=M/16),
// 4 waves each take K/4, LDS-reduce partials. Fixes R1's 64-block latency bind.
template<int NP>
__global__ __launch_bounds__(256)
void lora_t_kernel(const unsigned short* __restrict__ act,
                   const unsigned short* __restrict__ Ab,
                   unsigned short* __restrict__ tout, int K, int coloff){
  __shared__ float red[4][NP][4][64];
  const int tid = threadIdx.x, lane = tid & 63, wave = tid >> 6;
  const int m0 = blockIdx.x * 16;
  const int q = lane >> 4, r = lane & 15;
  const int KW = K >> 2;                 // per-wave K chunk
  const int kbase = wave * KW;
  const unsigned short* ap = act + (size_t)(m0 + r) * K + kbase + q * 8;
  const unsigned short* bp[NP];
  #pragma unroll
  for (int p = 0; p < NP; ++p)
    bp[p] = Ab + (size_t)(p * 16 + r) * K + kbase + q * 8;
  f32x4 acc[NP];
  #pragma unroll
  for (int p = 0; p < NP; ++p) acc[p] = (f32x4){0.f,0.f,0.f,0.f};
  for (int k = 0; k < KW; k += 32){
    const s16x8 a = *(const s16x8*)ap; ap += 32;
    #pragma unroll
    for (int p = 0; p < NP; ++p){
      const s16x8 b = *(const s16x8*)bp[p]; bp[p] += 32;
      acc[p] = __builtin_amdgcn_mfma_f32_16x16x32_bf16(a, b, acc[p], 0, 0, 0);
    }
  }
  #pragma unroll
  for (int p = 0; p < NP; ++p)
    #pragma unroll
    for (int rr = 0; rr < 4; ++rr) red[wave][p][rr][lane] = acc[p][rr];
  __syncthreads();
  // D layout: row m = (lane>>4)*4 + reg, col = lane&15 [measured m89]
  const int rr = tid >> 6, li = tid & 63;
  #pragma unroll
  for (int p = 0; p < NP; ++p){
    const float v = red[0][p][rr][li] + red[1][p][rr][li]
                  + red[2][p][rr][li] + red[3][p][rr][li];
    const int row = m0 + (li >> 4) * 4 + rr;
    const int col = coloff + p * 16 + (li & 15);
    tout[(size_t)row * 64 + col] = f2bf(v);
  }
}

// h = silu(gate) * up ; gu is [M, 2I] with gate in cols [0,I), up in [I,2I)
__global__ void silu_mul_kernel(unsigned short* __restrict__ h,
                                const unsigned short* __restrict__ gu){
  const int k8 = blockIdx.x * blockDim.x + threadIdx.x;  // < I/8 = 1792
  const size_t row = blockIdx.y;
  const s16x8 g8 = *(const s16x8*)(gu + row * 28672 + (size_t)k8 * 8);
  const s16x8 u8 = *(const s16x8*)(gu + row * 28672 + 14336 + (size_t)k8 * 8);
  s16x8 o;
  #pragma unroll
  for (int e = 0; e < 8; ++e){
    const float g = bf2f((unsigned short)g8[e]);
    const float u = bf2f((unsigned short)u8[e]);
    const float s = g / (1.f + __expf(-g));
    o[e] = (short)f2bf(s * u);
  }
  *(s16x8*)(h + row * 14336 + (size_t)k8 * 8) = o;
}

// ---------------------------------------------------------------------------
// Main GEMM: C[M,N] = A[M,K] @ B[N,K]^T, bf16 in / fp32 acc.
// 128x128 tile, 256 thr = 4 waves (2x2), wave does 64x64 via 4x4 mfma 16x16x32.
// Staging: global_load_lds 16B/lane, XOR chunk swizzle (col^=row&7) so the
// ds_read_b128 fragment reads are 2-way-conflict-only (free, m136).
// Lora is one extra K=64 iteration sourced from tL[M,64]/bL[N,64] (zero-padded).
// EPI: 0 = store bf16; 1 = o-proj (x1 = res + v, store fp32+bf16); 2 = down (out = res + v, fp32).
template<int EPI>
__global__ __launch_bounds__(256)
void gemm_kernel(const unsigned short* __restrict__ Aact,
                 const unsigned short* __restrict__ Bw,
                 const unsigned short* __restrict__ tL,
                 const unsigned short* __restrict__ bL,
                 int K, int ldC,
                 const float* __restrict__ resIn,
                 float* __restrict__ outF,
                 unsigned short* __restrict__ outB){
  __shared__ unsigned short As[128 * 64];
  __shared__ unsigned short Bs[128 * 64];
  const int tid  = threadIdx.x;
  const int lane = tid & 63;
  const int wave = tid >> 6;
  const int m0 = blockIdx.x << 7;   // x = M tiles so consecutive blocks share B-panel
  const int n0 = blockIdx.y << 7;

  // staging map: chunk c = tid + 256p ; row = c/8, slot-col = c%8, data-col = slot^ (row&7)
  const int srow  = tid >> 3;
  const int scol  = tid & 7;
  const int swcol = scol ^ (srow & 7);
  const unsigned short* gA = Aact + (size_t)(m0 + srow) * K + swcol * 8;
  const unsigned short* gB = Bw   + (size_t)(n0 + srow) * K + swcol * 8;
  const int ldsbase = wave * 512;   // wave*64 chunks * 8 shorts

  const int wm = wave >> 1, wn = wave & 1;
  const int q = lane >> 4, r15 = lane & 15;
  int aoff[4][2], boff[4][2];
  #pragma unroll
  for (int i = 0; i < 4; ++i){
    const int ml = wm*64 + i*16 + r15;
    const int nl = wn*64 + i*16 + r15;
    #pragma unroll
    for (int kk = 0; kk < 2; ++kk){
      aoff[i][kk] = ml*64 + ((((kk<<2)|q) ^ (ml & 7)) * 8);
      boff[i][kk] = nl*64 + ((((kk<<2)|q) ^ (nl & 7)) * 8);
    }
  }

  f32x4 acc[4][4];
  #pragma unroll
  for (int i = 0; i < 4; ++i)
    #pragma unroll
    for (int j = 0; j < 4; ++j) acc[i][j] = (f32x4){0.f,0.f,0.f,0.f};

  const int nK = K >> 6;
  size_t koff = 0;
  for (int kt = 0; kt <= nK; ++kt){
    const unsigned short* pa; const unsigned short* pb; size_t rs;
    if (kt < nK){ pa = gA + koff; pb = gB + koff; rs = (size_t)K * 32; }
    else {  // lora extra iteration: [*,64] row-major, row stride 64
      pa = tL + (size_t)(m0 + srow) * 64 + swcol * 8;
      pb = bL + (size_t)(n0 + srow) * 64 + swcol * 8;
      rs = 64 * 32;
    }
    #pragma unroll
    for (int p = 0; p < 4; ++p){
      gll16(pa + rs * p, As + ldsbase + p * 2048);
      gll16(pb + rs * p, Bs + ldsbase + p * 2048);
    }
    __syncthreads();                       // drains vmcnt(0) + barrier
    #pragma unroll
    for (int kk = 0; kk < 2; ++kk){
      s16x8 af[4], bfr[4];
      #pragma unroll
      for (int i = 0; i < 4; ++i) af[i]  = *(const s16x8*)(As + aoff[i][kk]);
      #pragma unroll
      for (int j = 0; j < 4; ++j) bfr[j] = *(const s16x8*)(Bs + boff[j][kk]);
      #pragma unroll
      for (int i = 0; i < 4; ++i)
        #pragma unroll
        for (int j = 0; j < 4; ++j)
          acc[i][j] = __builtin_amdgcn_mfma_f32_16x16x32_bf16(af[i], bfr[j], acc[i][j], 0, 0, 0);
    }
    __syncthreads();                       // LDS safe to overwrite
    koff += 64;
  }

  // epilogue: D row m = quad*4+reg, col n = lane&15 [measured m89]
  #pragma unroll
  for (int i = 0; i < 4; ++i){
    const int gm = m0 + wm*64 + i*16 + q*4;
    #pragma unroll
    for (int j = 0; j < 4; ++j){
      const int gn = n0 + wn*64 + j*16 + r15;
      #pragma unroll
      for (int rr = 0; rr < 4; ++rr){
        const size_t idx = (size_t)(gm + rr) * ldC + gn;
        const float v = acc[i][j][rr];
        if constexpr (EPI == 0){
          outB[idx] = f2bf(v);
        } else if constexpr (EPI == 1){
          const float x1 = resIn[idx] + v;
          outF[idx] = x1;
          outB[idx] = f2bf(x1);
        } else {
          outF[idx] = resIn[idx] + v;
        }
      }
    }
  }
}

// ---------------------------------------------------------------------------
extern "C" void kernel_launch(void* const* d_in, const int* in_sizes, int n_in,
                              void* d_out, int out_size, void* d_ws, size_t ws_size,
                              hipStream_t stream){
  (void)in_sizes; (void)n_in; (void)out_size; (void)ws_size;
  constexpr int M = 4096, H = 4096, I = 14336, I2 = 28672;

  const float* x            = (const float*)d_in[0];
  const int*   codes_attn   = (const int*)  d_in[1];
  const float* scales_attn  = (const float*)d_in[2];
  const int*   codes_gu     = (const int*)  d_in[3];
  const float* scales_gu    = (const float*)d_in[4];
  const int*   codes_down   = (const int*)  d_in[5];
  const float* scales_down  = (const float*)d_in[6];
  const float* lora_A_h     = (const float*)d_in[7];
  const float* lora_A_down  = (const float*)d_in[8];
  const float* lora_B_attn  = (const float*)d_in[9];
  const float* lora_B_gu    = (const float*)d_in[10];
  const float* lora_B_down  = (const float*)d_in[11];
  float* out = (float*)d_out;

  char* ws = (char*)d_ws;
  size_t off = 0;
  auto take = [&](size_t b){ void* p = ws + off; off += b; return p; };
  unsigned short* xb    = (unsigned short*)take((size_t)M*H*2);    // x as bf16
  unsigned short* W1    = (unsigned short*)take((size_t)H*H*2);    // Wsum, then Wo
  unsigned short* attn  = (unsigned short*)take((size_t)M*H*2);
  float*          x1f   = (float*)         take((size_t)M*H*4);
  unsigned short* x1b   = (unsigned short*)take((size_t)M*H*2);
  unsigned short* Wgu   = (unsigned short*)take((size_t)I2*H*2);   // then Wd
  unsigned short* gu    = (unsigned short*)take((size_t)M*I2*2);
  unsigned short* hbuf  = (unsigned short*)take((size_t)M*I*2);
  unsigned short* t1    = (unsigned short*)take((size_t)M*64*2);   // zeroed arena starts here
  unsigned short* t2    = (unsigned short*)take((size_t)M*64*2);
  unsigned short* t3    = (unsigned short*)take((size_t)M*64*2);
  unsigned short* t4    = (unsigned short*)take((size_t)M*64*2);
  unsigned short* bl_at = (unsigned short*)take((size_t)H*64*2);
  unsigned short* bl_o  = (unsigned short*)take((size_t)H*64*2);
  unsigned short* bl_gu = (unsigned short*)take((size_t)I2*64*2);
  unsigned short* bl_dn = (unsigned short*)take((size_t)H*64*2);
  const size_t zbytes = (size_t)((char*)ws + off - (char*)t1);
  unsigned short* al_h  = (unsigned short*)take((size_t)6*16*H*2); // lora A (h-side) bf16
  unsigned short* al_dn = (unsigned short*)take((size_t)16*I*2);   // lora A down bf16

  // zero the t / bl arena (ws is poisoned 0xAA before every call)
  hipMemsetAsync(t1, 0, zbytes, stream);

  // casts
  cast_f32_bf16<<<dim3((M*(size_t)H/8)/256), 256, 0, stream>>>(xb, x, (long long)M*H/8);
  cast_f32_bf16<<<dim3(192), 256, 0, stream>>>(al_h,  lora_A_h,    (long long)6*16*H/8);
  cast_f32_bf16<<<dim3(112), 256, 0, stream>>>(al_dn, lora_A_down, (long long)16*I/8);

  // pack lora B panels into [N,64] bf16
  for (int p = 0; p < 3; ++p)
    pack_bl_kernel<<<dim3(256), 256, 0, stream>>>(bl_at, lora_B_attn + (size_t)p*H*16, H, p*16, 1.f/3.f);
  pack_bl_kernel<<<dim3(256), 256, 0, stream>>>(bl_o, lora_B_attn + (size_t)3*H*16, H, 0, 1.f);
  pack_bl_kernel<<<dim3(896), 256, 0, stream>>>(bl_gu, lora_B_gu, I, 0, 1.f);
  pack_bl_kernel<<<dim3(896), 256, 0, stream>>>(bl_gu + (size_t)I*64, lora_B_gu + (size_t)I*16, I, 16, 1.f);
  pack_bl_kernel<<<dim3(256), 256, 0, stream>>>(bl_dn, lora_B_down, H, 0, 1.f);

  // t1 = xb @ [Aq;Ak;Av]^T  (one fused NP=3 pass; 1/3 folded into bl_at)
  lora_t_kernel<3><<<dim3(M/16), 256, 0, stream>>>(xb, al_h, t1, H, 0);

  // G1: attn = xb @ Wsum^T + lora      (Wsum = (Wq+Wk+Wv)/3)
  dequant3_kernel<<<dim3(H/2048, H), 256, 0, stream>>>(W1, codes_attn, scales_attn, H, 1.f/3.f);
  gemm_kernel<0><<<dim3(32, 32), 256, 0, stream>>>(xb, W1, t1, bl_at, H, H, nullptr, nullptr, attn);

  // G2: x1 = x + attn @ Wo^T + lora
  dequant1_kernel<<<dim3(H/2048, H), 256, 0, stream>>>(W1, codes_attn + (size_t)3*H*H,
                                                       scales_attn + (size_t)3*H*64, H, 1.f);
  lora_t_kernel<1><<<dim3(M/16), 256, 0, stream>>>(attn, al_h + (size_t)3*16*H, t2, H, 0);
  gemm_kernel<1><<<dim3(32, 32), 256, 0, stream>>>(attn, W1, t2, bl_o, H, H, x, x1f, x1b);

  // G3: gu = x1 @ [Wg;Wu]^T + lora (gate cols [0,I), up cols [I,2I))
  lora_t_kernel<2><<<dim3(M/16), 256, 0, stream>>>(x1b, al_h + (size_t)4*16*H, t3, H, 0);
  dequant1_kernel<<<dim3(H/2048, I2), 256, 0, stream>>>(Wgu, codes_gu, scales_gu, H, 1.f);
  gemm_kernel<0><<<dim3(32, 224), 256, 0, stream>>>(x1b, Wgu, t3, bl_gu, H, I2, nullptr, nullptr, gu);

  // h = silu(g) * u
  silu_mul_kernel<<<dim3(I/2048, M), 256, 0, stream>>>(hbuf, gu);

  // G5: out = x1 + h @ Wd^T + lora
  lora_t_kernel<1><<<dim3(M/16), 256, 0, stream>>>(hbuf, al_dn, t4, I, 0);
  dequant1_kernel<<<dim3(I/2048, H), 256, 0, stream>>>(Wgu, codes_down, scales_down, I, 1.f);
  gemm_kernel<2><<<dim3(32, 32), 256, 0, stream>>>(hbuf, Wgu, t4, bl_dn, I, H, x1f, out, nullptr);
}

// Round 3
// 3172.063 us; speedup vs baseline: 1.1259x; 1.0156x over previous
//
#include <hip/hip_runtime.h>
#include <cstdint>

// ---------------------------------------------------------------------------
// QLoRA block: 4 big bf16-MFMA GEMMs + NF4 dequant + lora folded as extra K.
// M=4096 tokens, H=4096, I=14336, R=16. All bf16 handled as unsigned short.
// R3: (1) silu fused into G3 epilogue via gate/up row-interleaved Wgu +
//     shfl_xor pairing (kills silu kernel + 470 MB of gu traffic);
//     (2) dequant rides inside GEMM launches as extra grid-y blocks
//     (tail-fill + BW hiding: GEMM runs at only 18% HBM).
// ---------------------------------------------------------------------------

typedef __attribute__((ext_vector_type(4))) float f32x4;
typedef __attribute__((ext_vector_type(8))) short s16x8;
typedef __attribute__((ext_vector_type(4))) int   i32x4;

__constant__ float NF4_TBL[16] = {
  -1.0f, -0.6961928009986877f, -0.5250730514526367f, -0.39491748809814453f,
  -0.28444138169288635f, -0.18477343022823334f, -0.09105003625154495f, 0.0f,
   0.07958029955625534f, 0.16093020141124725f, 0.24611230194568634f,
   0.33791524171829224f, 0.44070982933044434f, 0.5626170039176941f,
   0.7229568362236023f, 1.0f };

__device__ __forceinline__ unsigned short f2bf(float f){
  unsigned u = __builtin_bit_cast(unsigned, f);
  u += 0x7fffu + ((u >> 16) & 1u);              // RNE
  return (unsigned short)(u >> 16);
}
__device__ __forceinline__ float bf2f(unsigned short h){
  return __builtin_bit_cast(float, ((unsigned)h) << 16);
}

// async global->LDS, 16B per lane. LDS dst must be wave-uniform base (lane*16 implicit).
__device__ __forceinline__ void gll16(const unsigned short* g, unsigned short* l){
  __builtin_amdgcn_global_load_lds((__attribute__((address_space(1))) unsigned int*)g,
                                   (__attribute__((address_space(3))) unsigned int*)l,
                                   16, 0, 0);
}

// ---------------------------------------------------------------------------
// NF4 dequant job descriptor (run by ride-along blocks inside gemm launches).
// ilv=1: dst row n <- plane (n&1), source row (n>>1)  [gate/up interleave]
struct DeqP {
  unsigned short* dst;
  const int* c0; const int* c1;
  const float* s0; const float* s1;
  int K; int rows; int ilv;
};

__device__ void deq_rows(const DeqP& p, int bid, int nb){
  const int K8 = p.K >> 3;
  for (int n = bid; n < p.rows; n += nb){
    const int plane = p.ilv ? (n & 1) : 0;
    const int sr    = p.ilv ? (n >> 1) : n;
    const int*   cp = (plane ? p.c1 : p.c0) + (size_t)sr * p.K;
    const float* sp = (plane ? p.s1 : p.s0) + (size_t)sr * (p.K >> 6);
    unsigned short* dp = p.dst + (size_t)n * p.K;
    for (int k8 = threadIdx.x; k8 < K8; k8 += 256){
      const int k = k8 * 8;
      const float s = sp[k >> 6];
      const i32x4 c0 = *(const i32x4*)(cp + k);
      const i32x4 c1 = *(const i32x4*)(cp + k + 4);
      s16x8 o;
      o[0]=(short)f2bf(NF4_TBL[c0.x]*s); o[1]=(short)f2bf(NF4_TBL[c0.y]*s);
      o[2]=(short)f2bf(NF4_TBL[c0.z]*s); o[3]=(short)f2bf(NF4_TBL[c0.w]*s);
      o[4]=(short)f2bf(NF4_TBL[c1.x]*s); o[5]=(short)f2bf(NF4_TBL[c1.y]*s);
      o[6]=(short)f2bf(NF4_TBL[c1.z]*s); o[7]=(short)f2bf(NF4_TBL[c1.w]*s);
      *(s16x8*)(dp + k) = o;
    }
  }
}

// ---------------------------------------------------------------------------
// elementwise fp32 -> bf16 (8 elems/thread)
__global__ void cast_f32_bf16(unsigned short* __restrict__ dst,
                              const float* __restrict__ src, long long n8){
  const long long i = (long long)blockIdx.x * blockDim.x + threadIdx.x;
  if (i >= n8) return;
  const f32x4 a = *(const f32x4*)(src + i*8);
  const f32x4 b = *(const f32x4*)(src + i*8 + 4);
  s16x8 o;
  o[0]=(short)f2bf(a.x); o[1]=(short)f2bf(a.y); o[2]=(short)f2bf(a.z); o[3]=(short)f2bf(a.w);
  o[4]=(short)f2bf(b.x); o[5]=(short)f2bf(b.y); o[6]=(short)f2bf(b.z); o[7]=(short)f2bf(b.w);
  *(s16x8*)(dst + i*8) = o;
}

// pack lora B [N,16] fp32 -> bf16 [N*rmul+radd, 64] at column offset
__global__ void pack_bl_kernel(unsigned short* __restrict__ dst,
                               const float* __restrict__ src,
                               int N, int coloff, float mul, int rmul, int radd){
  const int i = blockIdx.x * blockDim.x + threadIdx.x;
  if (i >= N * 16) return;
  const int n = i >> 4, r = i & 15;
  dst[(size_t)(n * rmul + radd) * 64 + coloff + r] = f2bf(src[i] * mul);
}

// Wsum = (Wq + Wk + Wv) * mul, dequantized on the fly (H=4096 hardcoded strides)
__global__ void dequant3_kernel(unsigned short* __restrict__ dst,
                                const int* __restrict__ codes,
                                const float* __restrict__ scales, int K, float mul){
  const int k = (blockIdx.x * blockDim.x + threadIdx.x) * 8;
  if (k >= K) return;
  const size_t n = blockIdx.y;
  const size_t base = n * (size_t)K + k;
  const size_t CS = (size_t)4096 * 4096;
  const size_t SS = (size_t)4096 * 64;
  float acc[8] = {0.f,0.f,0.f,0.f,0.f,0.f,0.f,0.f};
  #pragma unroll
  for (int t = 0; t < 3; ++t){
    const float s = scales[t * SS + n * (size_t)(K >> 6) + (k >> 6)];
    const i32x4 c0 = *(const i32x4*)(codes + t * CS + base);
    const i32x4 c1 = *(const i32x4*)(codes + t * CS + base + 4);
    acc[0]+=NF4_TBL[c0.x]*s; acc[1]+=NF4_TBL[c0.y]*s; acc[2]+=NF4_TBL[c0.z]*s; acc[3]+=NF4_TBL[c0.w]*s;
    acc[4]+=NF4_TBL[c1.x]*s; acc[5]+=NF4_TBL[c1.y]*s; acc[6]+=NF4_TBL[c1.z]*s; acc[7]+=NF4_TBL[c1.w]*s;
  }
  s16x8 o;
  #pragma unroll
  for (int e = 0; e < 8; ++e) o[e] = (short)f2bf(acc[e] * mul);
  *(s16x8*)(dst + base) = o;
}

// ---------------------------------------------------------------------------
// t = act[M,K] @ Ab[NP*16,K]^T -> tout[M,64] bf16, panel p lands at cols
// [coloff+16p, ...). Split-K: one block per 16-row M-tile (grid=M/16),
// 4 waves each take K/4, LDS-reduce partials.
template<int NP>
__global__ __launch_bounds__(256)
void lora_t_kernel(const unsigned short* __restrict__ act,
                   const unsigned short* __restrict__ Ab,
                   unsigned short* __restrict__ tout, int K, int coloff){
  __shared__ float red[4][NP][4][64];
  const int tid = threadIdx.x, lane = tid & 63, wave = tid >> 6;
  const int m0 = blockIdx.x * 16;
  const int q = lane >> 4, r = lane & 15;
  const int KW = K >> 2;                 // per-wave K chunk
  const int kbase = wave * KW;
  const unsigned short* ap = act + (size_t)(m0 + r) * K + kbase + q * 8;
  const unsigned short* bp[NP];
  #pragma unroll
  for (int p = 0; p < NP; ++p)
    bp[p] = Ab + (size_t)(p * 16 + r) * K + kbase + q * 8;
  f32x4 acc[NP];
  #pragma unroll
  for (int p = 0; p < NP; ++p) acc[p] = (f32x4){0.f,0.f,0.f,0.f};
  for (int k = 0; k < KW; k += 32){
    const s16x8 a = *(const s16x8*)ap; ap += 32;
    #pragma unroll
    for (int p = 0; p < NP; ++p){
      const s16x8 b = *(const s16x8*)bp[p]; bp[p] += 32;
      acc[p] = __builtin_amdgcn_mfma_f32_16x16x32_bf16(a, b, acc[p], 0, 0, 0);
    }
  }
  #pragma unroll
  for (int p = 0; p < NP; ++p)
    #pragma unroll
    for (int rr = 0; rr < 4; ++rr) red[wave][p][rr][lane] = acc[p][rr];
  __syncthreads();
  // D layout: row m = (lane>>4)*4 + reg, col = lane&15 [measured m89]
  const int rr = tid >> 6, li = tid & 63;
  #pragma unroll
  for (int p = 0; p < NP; ++p){
    const float v = red[0][p][rr][li] + red[1][p][rr][li]
                  + red[2][p][rr][li] + red[3][p][rr][li];
    const int row = m0 + (li >> 4) * 4 + rr;
    const int col = coloff + p * 16 + (li & 15);
    tout[(size_t)row * 64 + col] = f2bf(v);
  }
}

// ---------------------------------------------------------------------------
// Main GEMM: C[M,N] = A[M,K] @ B[N,K]^T, bf16 in / fp32 acc.
// 128x128 tile, 256 thr = 4 waves (2x2), wave does 64x64 via 4x4 mfma 16x16x32.
// Staging: global_load_lds 16B/lane, XOR chunk swizzle (col^=row&7).
// Lora is one extra K=64 iteration from tL[M,64]/bL[N,64] (zero-padded).
// Blocks with blockIdx.y >= NY run NF4 dequant jobs instead (tail-fill; they
// dispatch last, using the GEMM's spare HBM BW — GEMM is only ~18% HBM-busy).
// EPI: 0 = store bf16; 1 = x1 = res + v (fp32+bf16); 2 = out = res + v (fp32);
//      3 = gate/up interleaved -> h = silu(g)*u, bf16, h-col = gn/2.
template<int EPI>
__global__ __launch_bounds__(256)
void gemm_kernel(const unsigned short* __restrict__ Aact,
                 const unsigned short* __restrict__ Bw,
                 const unsigned short* __restrict__ tL,
                 const unsigned short* __restrict__ bL,
                 int K, int ldC,
                 const float* __restrict__ resIn,
                 float* __restrict__ outF,
                 unsigned short* __restrict__ outB,
                 int NY, DeqP dqa, DeqP dqb){
  if ((int)blockIdx.y >= NY){
    const int bid = ((int)blockIdx.y - NY) * gridDim.x + blockIdx.x;
    const int nb  = ((int)gridDim.y - NY) * gridDim.x;
    if (dqa.rows) deq_rows(dqa, bid, nb);
    if (dqb.rows) deq_rows(dqb, bid, nb);
    return;
  }
  __shared__ unsigned short As[128 * 64];
  __shared__ unsigned short Bs[128 * 64];
  const int tid  = threadIdx.x;
  const int lane = tid & 63;
  const int wave = tid >> 6;
  const int m0 = blockIdx.x << 7;   // x = M tiles so consecutive blocks share B-panel
  const int n0 = blockIdx.y << 7;

  // staging map: chunk c = tid + 256p ; row = c/8, slot-col = c%8, data-col = slot^(row&7)
  const int srow  = tid >> 3;
  const int scol  = tid & 7;
  const int swcol = scol ^ (srow & 7);
  const unsigned short* gA = Aact + (size_t)(m0 + srow) * K + swcol * 8;
  const unsigned short* gB = Bw   + (size_t)(n0 + srow) * K + swcol * 8;
  const int ldsbase = wave * 512;   // wave*64 chunks * 8 shorts

  const int wm = wave >> 1, wn = wave & 1;
  const int q = lane >> 4, r15 = lane & 15;
  int aoff[4][2], boff[4][2];
  #pragma unroll
  for (int i = 0; i < 4; ++i){
    const int ml = wm*64 + i*16 + r15;
    const int nl = wn*64 + i*16 + r15;
    #pragma unroll
    for (int kk = 0; kk < 2; ++kk){
      aoff[i][kk] = ml*64 + ((((kk<<2)|q) ^ (ml & 7)) * 8);
      boff[i][kk] = nl*64 + ((((kk<<2)|q) ^ (nl & 7)) * 8);
    }
  }

  f32x4 acc[4][4];
  #pragma unroll
  for (int i = 0; i < 4; ++i)
    #pragma unroll
    for (int j = 0; j < 4; ++j) acc[i][j] = (f32x4){0.f,0.f,0.f,0.f};

  const int nK = K >> 6;
  size_t koff = 0;
  for (int kt = 0; kt <= nK; ++kt){
    const unsigned short* pa; const unsigned short* pb; size_t rs;
    if (kt < nK){ pa = gA + koff; pb = gB + koff; rs = (size_t)K * 32; }
    else {  // lora extra iteration: [*,64] row-major, row stride 64
      pa = tL + (size_t)(m0 + srow) * 64 + swcol * 8;
      pb = bL + (size_t)(n0 + srow) * 64 + swcol * 8;
      rs = 64 * 32;
    }
    #pragma unroll
    for (int p = 0; p < 4; ++p){
      gll16(pa + rs * p, As + ldsbase + p * 2048);
      gll16(pb + rs * p, Bs + ldsbase + p * 2048);
    }
    __syncthreads();                       // drains vmcnt(0) + barrier
    #pragma unroll
    for (int kk = 0; kk < 2; ++kk){
      s16x8 af[4], bfr[4];
      #pragma unroll
      for (int i = 0; i < 4; ++i) af[i]  = *(const s16x8*)(As + aoff[i][kk]);
      #pragma unroll
      for (int j = 0; j < 4; ++j) bfr[j] = *(const s16x8*)(Bs + boff[j][kk]);
      #pragma unroll
      for (int i = 0; i < 4; ++i)
        #pragma unroll
        for (int j = 0; j < 4; ++j)
          acc[i][j] = __builtin_amdgcn_mfma_f32_16x16x32_bf16(af[i], bfr[j], acc[i][j], 0, 0, 0);
    }
    __syncthreads();                       // LDS safe to overwrite
    koff += 64;
  }

  // epilogue: D row m = quad*4+reg, col n = lane&15 [measured m89]
  #pragma unroll
  for (int i = 0; i < 4; ++i){
    const int gm = m0 + wm*64 + i*16 + q*4;
    #pragma unroll
    for (int j = 0; j < 4; ++j){
      const int gn = n0 + wn*64 + j*16 + r15;
      #pragma unroll
      for (int rr = 0; rr < 4; ++rr){
        const float v = acc[i][j][rr];
        if constexpr (EPI == 3){
          // gate/up pair in adjacent lanes: even lane = gate, odd = up
          const float other = __shfl_xor(v, 1);
          if ((r15 & 1) == 0){
            const float sg = v / (1.f + __expf(-v));
            outB[(size_t)(gm + rr) * ldC + (gn >> 1)] = f2bf(sg * other);
          }
        } else {
          const size_t idx = (size_t)(gm + rr) * ldC + gn;
          if constexpr (EPI == 0){
            outB[idx] = f2bf(v);
          } else if constexpr (EPI == 1){
            const float x1 = resIn[idx] + v;
            outF[idx] = x1;
            outB[idx] = f2bf(x1);
          } else {
            outF[idx] = resIn[idx] + v;
          }
        }
      }
    }
  }
}

// ---------------------------------------------------------------------------
extern "C" void kernel_launch(void* const* d_in, const int* in_sizes, int n_in,
                              void* d_out, int out_size, void* d_ws, size_t ws_size,
                              hipStream_t stream){
  (void)in_sizes; (void)n_in; (void)out_size; (void)ws_size;
  constexpr int M = 4096, H = 4096, I = 14336, I2 = 28672;
  constexpr int IH = 7168;     // half of I (Wgu dequant split across G1/G2)

  const float* x            = (const float*)d_in[0];
  const int*   codes_attn   = (const int*)  d_in[1];
  const float* scales_attn  = (const float*)d_in[2];
  const int*   codes_gu     = (const int*)  d_in[3];
  const float* scales_gu    = (const float*)d_in[4];
  const int*   codes_down   = (const int*)  d_in[5];
  const float* scales_down  = (const float*)d_in[6];
  const float* lora_A_h     = (const float*)d_in[7];
  const float* lora_A_down  = (const float*)d_in[8];
  const float* lora_B_attn  = (const float*)d_in[9];
  const float* lora_B_gu    = (const float*)d_in[10];
  const float* lora_B_down  = (const float*)d_in[11];
  float* out = (float*)d_out;

  char* ws = (char*)d_ws;
  size_t off = 0;
  auto take = [&](size_t b){ void* p = ws + off; off += b; return p; };
  unsigned short* xb    = (unsigned short*)take((size_t)M*H*2);    // x as bf16
  unsigned short* W1    = (unsigned short*)take((size_t)H*I*2);    // Wsum(HxH), later Wd(HxI)
  unsigned short* W2    = (unsigned short*)take((size_t)H*H*2);    // Wo (dequant rides G1)
  unsigned short* attn  = (unsigned short*)take((size_t)M*H*2);
  float*          x1f   = (float*)         take((size_t)M*H*4);
  unsigned short* x1b   = (unsigned short*)take((size_t)M*H*2);
  unsigned short* Wgu   = (unsigned short*)take((size_t)I2*H*2);   // gate/up row-interleaved
  unsigned short* hbuf  = (unsigned short*)take((size_t)M*I*2);
  unsigned short* t1    = (unsigned short*)take((size_t)M*64*2);   // zeroed arena starts here
  unsigned short* t2    = (unsigned short*)take((size_t)M*64*2);
  unsigned short* t3    = (unsigned short*)take((size_t)M*64*2);
  unsigned short* t4    = (unsigned short*)take((size_t)M*64*2);
  unsigned short* bl_at = (unsigned short*)take((size_t)H*64*2);
  unsigned short* bl_o  = (unsigned short*)take((size_t)H*64*2);
  unsigned short* bl_gu = (unsigned short*)take((size_t)I2*64*2);  // interleaved rows
  unsigned short* bl_dn = (unsigned short*)take((size_t)H*64*2);
  const size_t zbytes = (size_t)((char*)ws + off - (char*)t1);
  unsigned short* al_h  = (unsigned short*)take((size_t)6*16*H*2); // lora A (h-side) bf16
  unsigned short* al_dn = (unsigned short*)take((size_t)16*I*2);   // lora A down bf16

  // zero the t / bl arena (ws is poisoned 0xAA before every call)
  hipMemsetAsync(t1, 0, zbytes, stream);

  // casts
  cast_f32_bf16<<<dim3((M*(size_t)H/8)/256), 256, 0, stream>>>(xb, x, (long long)M*H/8);
  cast_f32_bf16<<<dim3(192), 256, 0, stream>>>(al_h,  lora_A_h,    (long long)6*16*H/8);
  cast_f32_bf16<<<dim3(112), 256, 0, stream>>>(al_dn, lora_A_down, (long long)16*I/8);

  // pack lora B panels into [N,64] bf16 (gu: row-interleaved to match Wgu)
  for (int p = 0; p < 3; ++p)
    pack_bl_kernel<<<dim3(256), 256, 0, stream>>>(bl_at, lora_B_attn + (size_t)p*H*16, H, p*16, 1.f/3.f, 1, 0);
  pack_bl_kernel<<<dim3(256), 256, 0, stream>>>(bl_o, lora_B_attn + (size_t)3*H*16, H, 0, 1.f, 1, 0);
  pack_bl_kernel<<<dim3(896), 256, 0, stream>>>(bl_gu, lora_B_gu, I, 0, 1.f, 2, 0);                    // gate -> rows 2j, cols 0-15
  pack_bl_kernel<<<dim3(896), 256, 0, stream>>>(bl_gu, lora_B_gu + (size_t)I*16, I, 16, 1.f, 2, 1);    // up   -> rows 2j+1, cols 16-31
  pack_bl_kernel<<<dim3(256), 256, 0, stream>>>(bl_dn, lora_B_down, H, 0, 1.f, 1, 0);

  // Wsum = (Wq+Wk+Wv)/3 (standalone: nothing to hide under yet)
  dequant3_kernel<<<dim3(H/2048, H), 256, 0, stream>>>(W1, codes_attn, scales_attn, H, 1.f/3.f);

  // t1 = xb @ [Aq;Ak;Av]^T  (one fused NP=3 pass; 1/3 folded into bl_at)
  lora_t_kernel<3><<<dim3(M/16), 256, 0, stream>>>(xb, al_h, t1, H, 0);

  const DeqP dq0{};  // empty
  // G1: attn = xb @ Wsum^T + lora. Rides: dequant Wo -> W2, Wgu lower half (interleaved).
  {
    DeqP dWo { W2, codes_attn + (size_t)3*H*H, nullptr,
               scales_attn + (size_t)3*H*64, nullptr, H, H, 0 };
    DeqP dGuA{ Wgu, codes_gu, codes_gu + (size_t)I*H,
               scales_gu, scales_gu + (size_t)I*64, H, I, 1 };
    gemm_kernel<0><<<dim3(32, 64), 256, 0, stream>>>(xb, W1, t1, bl_at, H, H,
                                                     nullptr, nullptr, attn, 32, dWo, dGuA);
  }

  // G2: x1 = x + attn @ Wo^T + lora. Rides: dequant Wgu upper half.
  lora_t_kernel<1><<<dim3(M/16), 256, 0, stream>>>(attn, al_h + (size_t)3*16*H, t2, H, 0);
  {
    DeqP dGuB{ Wgu + (size_t)I*H, codes_gu + (size_t)IH*H, codes_gu + (size_t)I*H + (size_t)IH*H,
               scales_gu + (size_t)IH*64, scales_gu + (size_t)I*64 + (size_t)IH*64, H, I, 1 };
    gemm_kernel<1><<<dim3(32, 64), 256, 0, stream>>>(attn, W2, t2, bl_o, H, H,
                                                     x, x1f, x1b, 32, dGuB, dq0);
  }

  // G3: h = silu(g)*u fused epilogue over interleaved [Wg;Wu]. Rides: dequant Wd -> W1 slot.
  lora_t_kernel<2><<<dim3(M/16), 256, 0, stream>>>(x1b, al_h + (size_t)4*16*H, t3, H, 0);
  {
    DeqP dWd { W1, codes_down, nullptr, scales_down, nullptr, I, H, 0 };
    gemm_kernel<3><<<dim3(32, 224 + 32), 256, 0, stream>>>(x1b, Wgu, t3, bl_gu, H, I,
                                                           nullptr, nullptr, hbuf, 224, dWd, dq0);
  }

  // G5: out = x1 + h @ Wd^T + lora
  lora_t_kernel<1><<<dim3(M/16), 256, 0, stream>>>(hbuf, al_dn, t4, I, 0);
  gemm_kernel<2><<<dim3(32, 32), 256, 0, stream>>>(hbuf, W1, t4, bl_dn, I, H,
                                                   x1f, out, nullptr, 32, dq0, dq0);
}